// Round 1
// baseline (101.032 us; speedup 1.0000x reference)
//
#include <hip/hip_runtime.h>

// Conv2dfft == direct 3x3 cross-correlation, pad=1, + bias (FFT grid never wraps).
// x: [32,128,32,32] f32; w: [128,128,3,3] f32; b: [128] f32; out: [32,128,32,32] f32.
// R3: barrier-free K-loop. x staged ONCE in LDS (53KB, XOR-swizzled 16B chunks);
// weights (L2-hot, 294KB) loaded straight to registers as coalesced 16B loads.
// No per-chunk vmcnt(0) drains; compiler free to pipeline loads across the
// fully-unrolled 36-tap-chunk loop. Grid 512 (2 blocks/CU), 4 waves/block.

typedef __attribute__((ext_vector_type(8))) short bf16x8;
typedef __attribute__((ext_vector_type(4))) float f32x4;

#define N_IMG 32
#define C_IN  128
#define F_OUT 128
#define HW    32
#define HPAD  34

__device__ __forceinline__ unsigned short f2bf(float f) {
    union { float f; unsigned u; } v; v.f = f;
    unsigned r = v.u + 0x7fffu + ((v.u >> 16) & 1u);   // RNE
    return (unsigned short)(r >> 16);
}

// ---------------- pack x: [N,C,32,32] f32 -> [N,34,34,C] bf16, zero border ----
__global__ __launch_bounds__(256) void pack_x_kernel(const float* __restrict__ x,
                                                     unsigned short* __restrict__ xp) {
    __shared__ unsigned short tile[C_IN * HPAD];   // [c][wp]
    const int n   = blockIdx.x / HPAD;
    const int hp  = blockIdx.x - n * HPAD;
    const int tid = threadIdx.x;
    const unsigned base_out = (unsigned)(n * HPAD + hp) * (HPAD * C_IN);
    if (hp >= 1 && hp <= 32) {
        const int h = hp - 1;
        #pragma unroll
        for (int i = 0; i < 16; ++i) {                 // 4096 = 128c * 32w, coalesced reads
            int idx = tid + i * 256;
            int c = idx >> 5, w = idx & 31;
            tile[c * HPAD + (w + 1)] = f2bf(x[((n * C_IN + c) * HW + h) * HW + w]);
        }
        if (tid < C_IN) { tile[tid * HPAD] = 0; tile[tid * HPAD + 33] = 0; }
        __syncthreads();
        #pragma unroll
        for (int i = 0; i < 17; ++i) {                 // 4352 = 34wp * 128c, coalesced writes
            int idx = tid + i * 256;
            int wp = idx >> 7, c = idx & 127;
            xp[base_out + (unsigned)idx] = tile[c * HPAD + wp];
        }
    } else {
        #pragma unroll
        for (int i = 0; i < 17; ++i) {
            int idx = tid + i * 256;
            xp[base_out + (unsigned)idx] = 0;
        }
    }
}

// ------- pack w: [F,C,3,3] f32 -> [cc 4][tap 9][f 128][ci 32] bf16 (cc outermost)
__global__ __launch_bounds__(256) void pack_w_kernel(const float* __restrict__ w,
                                                     unsigned short* __restrict__ wpk) {
    int idx = blockIdx.x * 256 + threadIdx.x;          // < 147456
    int ci = idx & 31;
    int f  = (idx >> 5) & 127;
    int u  = idx >> 12;                                // 0..35 = cc*9 + t
    int cc = u / 9;
    int t  = u - cc * 9;
    wpk[idx] = f2bf(w[(f * C_IN + cc * 32 + ci) * 9 + t]);
}

// ---------------- implicit-GEMM conv ----------------------------------------
// grid 512: (n 32) x (band 8: 4 output rows) x (f-half 2). Block 256 = 4 waves.
// Wave tile 64f x 32pos (one output row), acc[4][2].
// LDS: x tile staged ONCE: rows rr = dh*34+wp (dh 0..5, 204 real rows + 4 dump),
// 128 c per row = 16 x 16B chunks, phys chunk = logical ^ (rr & 15).
// Weights: per-(cc,tap,mi) 16B register loads from wpk (no LDS, no barriers).
__global__ __launch_bounds__(256, 2) void conv_gemm_kernel(
    const unsigned short* __restrict__ xp,
    const unsigned short* __restrict__ wpk,
    const float* __restrict__ bias,
    float* __restrict__ out)
{
    __shared__ alignas(16) unsigned short lds_x[208 * C_IN];   // 53,248 B

    const int tid  = threadIdx.x;
    const int lane = tid & 63;
    const int wave = tid >> 6;
    const int qk   = lane >> 4;      // k-group 0..3 (8 channels each)
    const int l15  = lane & 15;

    const int fh   = blockIdx.x & 1;
    const int band = (blockIdx.x >> 1) & 7;
    const int n    = blockIdx.x >> 4;
    const int f0   = fh * 64;
    const int h0   = band * 4;

    // ---- stage x once: 3328 16B chunks (rows 204..207 are dump, src clamped)
    const unsigned short* xbase = xp + (unsigned)((n * HPAD + h0) * HPAD) * C_IN;
    #pragma unroll
    for (int i = 0; i < 13; ++i) {
        int p = tid + i * 256;
        int row = p >> 4;  if (row > 203) row = 203;
        int lc = (p ^ row) & 15;                      // logical chunk for phys p&15
        const unsigned short* src = xbase + row * C_IN + lc * 8;
        __builtin_amdgcn_global_load_lds(
            (const __attribute__((address_space(1))) void*)src,
            (__attribute__((address_space(3))) void*)(&lds_x[p * 8]),
            16, 0, 0);
    }

    f32x4 acc[4][2];
    #pragma unroll
    for (int mi = 0; mi < 4; ++mi)
        #pragma unroll
        for (int ni = 0; ni < 2; ++ni)
            acc[mi][ni] = (f32x4){0.f, 0.f, 0.f, 0.f};

    // weight base for this lane: + cc*36864 + tap*4096 + mi*512 (shorts)
    const unsigned short* wbase = wpk + f0 * 32 + l15 * 32 + qk * 8;

    // x row bases per ni (element rows; + r*34 + s at use site)
    const int rrb0 = wave * HPAD + l15;
    const int rrb1 = wave * HPAD + 16 + l15;

    __syncthreads();   // x tile resident; only barrier in the kernel

    #pragma unroll
    for (int cc = 0; cc < 4; ++cc) {
        #pragma unroll
        for (int tap = 0; tap < 9; ++tap) {
            const int r = tap / 3, s = tap - 3 * (tap / 3);
            bf16x8 af[4], bf[2];
            #pragma unroll
            for (int mi = 0; mi < 4; ++mi)
                af[mi] = *(const bf16x8*)(wbase + cc * 36864 + tap * 4096 + mi * 512);
            {
                int rr0 = rrb0 + r * HPAD + s;
                int ph0 = (cc * 4 + qk) ^ (rr0 & 15);
                bf[0] = *(const bf16x8*)&lds_x[rr0 * C_IN + ph0 * 8];
                int rr1 = rrb1 + r * HPAD + s;
                int ph1 = (cc * 4 + qk) ^ (rr1 & 15);
                bf[1] = *(const bf16x8*)&lds_x[rr1 * C_IN + ph1 * 8];
            }
            #pragma unroll
            for (int mi = 0; mi < 4; ++mi)
                #pragma unroll
                for (int ni = 0; ni < 2; ++ni)
                    acc[mi][ni] = __builtin_amdgcn_mfma_f32_16x16x32_bf16(
                        af[mi], bf[ni], acc[mi][ni], 0, 0, 0);
        }
    }

    // ---- epilogue: D row (f) = qk*4 + reg, col (pos) = l15; wave owns out row h0+wave
    const int h = h0 + wave;
    #pragma unroll
    for (int mi = 0; mi < 4; ++mi) {
        const int f_base = f0 + mi * 16 + qk * 4;
        float bv[4];
        #pragma unroll
        for (int r2 = 0; r2 < 4; ++r2) bv[r2] = bias[f_base + r2];
        #pragma unroll
        for (int ni = 0; ni < 2; ++ni) {
            const int w2 = ni * 16 + l15;
            #pragma unroll
            for (int r2 = 0; r2 < 4; ++r2) {
                out[((unsigned)(n * F_OUT + f_base + r2) * HW + h) * HW + w2] =
                    acc[mi][ni][r2] + bv[r2];
            }
        }
    }
}

extern "C" void kernel_launch(void* const* d_in, const int* in_sizes, int n_in,
                              void* d_out, int out_size, void* d_ws, size_t ws_size,
                              hipStream_t stream) {
    const float* x = (const float*)d_in[0];
    const float* w = (const float*)d_in[1];
    const float* b = (const float*)d_in[2];
    float* out = (float*)d_out;

    unsigned short* xp  = (unsigned short*)d_ws;                   // 32*34*34*128 bf16
    unsigned short* wpk = xp + (size_t)N_IMG * HPAD * HPAD * C_IN; // 4*9*128*32 bf16

    pack_x_kernel<<<N_IMG * HPAD, 256, 0, stream>>>(x, xp);
    pack_w_kernel<<<576, 256, 0, stream>>>(w, wpk);
    conv_gemm_kernel<<<512, 256, 0, stream>>>(xp, wpk, b, out);
}

// Round 3
// 91.502 us; speedup vs baseline: 1.1042x; 1.1042x over previous
//
#include <hip/hip_runtime.h>

// Conv2dfft == direct 3x3 cross-correlation, pad=1, + bias (FFT grid never wraps).
// x: [32,128,32,32] f32; w: [128,128,3,3] f32; b: [128] f32; out: [32,128,32,32] f32.
// R5: R4 structure with the fh-offset bug fixed (LDS af read now adds fh*64 filters).
// Wave tile 64f x 64pos (acc[4][4]: 8 ds_reads / 16 MFMAs). Grid 256 (1 block/CU,
// 132KB LDS), 4 waves. x staged ONCE (53KB, XOR-swizzled 16B chunks). Weights staged
// in 8 half-cc phases, ping-pong 2x40KB, issued one phase AHEAD of compute, so global
// latency hides under MFMA+ds_read. Weight LDS layout [tap][qk][f128][8c] is
// bank-conflict-free for the af fragment read with no swizzle.

typedef __attribute__((ext_vector_type(8))) short bf16x8;
typedef __attribute__((ext_vector_type(4))) float f32x4;

#define N_IMG 32
#define C_IN  128
#define F_OUT 128
#define HW    32
#define HPAD  34

__device__ __forceinline__ unsigned short f2bf(float f) {
    union { float f; unsigned u; } v; v.f = f;
    unsigned r = v.u + 0x7fffu + ((v.u >> 16) & 1u);   // RNE
    return (unsigned short)(r >> 16);
}

// ---------------- pack x: [N,C,32,32] f32 -> [N,34,34,C] bf16, zero border ----
__global__ __launch_bounds__(256) void pack_x_kernel(const float* __restrict__ x,
                                                     unsigned short* __restrict__ xp) {
    __shared__ unsigned short tile[C_IN * HPAD];   // [c][wp]
    const int n   = blockIdx.x / HPAD;
    const int hp  = blockIdx.x - n * HPAD;
    const int tid = threadIdx.x;
    const unsigned base_out = (unsigned)(n * HPAD + hp) * (HPAD * C_IN);
    if (hp >= 1 && hp <= 32) {
        const int h = hp - 1;
        #pragma unroll
        for (int i = 0; i < 16; ++i) {                 // 4096 = 128c * 32w, coalesced reads
            int idx = tid + i * 256;
            int c = idx >> 5, w = idx & 31;
            tile[c * HPAD + (w + 1)] = f2bf(x[((n * C_IN + c) * HW + h) * HW + w]);
        }
        if (tid < C_IN) { tile[tid * HPAD] = 0; tile[tid * HPAD + 33] = 0; }
        __syncthreads();
        #pragma unroll
        for (int i = 0; i < 17; ++i) {                 // 4352 = 34wp * 128c, coalesced writes
            int idx = tid + i * 256;
            int wp = idx >> 7, c = idx & 127;
            xp[base_out + (unsigned)idx] = tile[c * HPAD + wp];
        }
    } else {
        #pragma unroll
        for (int i = 0; i < 17; ++i) {
            int idx = tid + i * 256;
            xp[base_out + (unsigned)idx] = 0;
        }
    }
}

// ------- pack w: [F,C,3,3] f32 -> [cc 4][tap 9][qk 4][f 128][c8 8] bf16 -------
// (qk = 8-channel subgroup within the cc's 32 channels). Linear for staging,
// conflict-free for the af fragment ds_read.
__global__ __launch_bounds__(256) void pack_w_kernel(const float* __restrict__ w,
                                                     unsigned short* __restrict__ wpk) {
    int idx = blockIdx.x * 256 + threadIdx.x;          // < 147456
    int c8  = idx & 7;
    int f   = (idx >> 3) & 127;
    int qk  = (idx >> 10) & 3;
    int u   = idx >> 12;                               // 0..35 = cc*9 + tap
    int cc  = u / 9;
    int tap = u - cc * 9;
    wpk[idx] = f2bf(w[(f * C_IN + cc * 32 + qk * 8 + c8) * 9 + tap]);
}

// ---------------- implicit-GEMM conv ----------------------------------------
// grid 256: (n 32) x (band 8: 4 output rows). Block 256 = 4 waves, 1 block/CU.
// Wave (fh = wave>>1, rp = wave&1): tile 64f x 64pos (2 rows x 32), acc[4][4].
// LDS: x tile (rows rr = dh*34+wp, dh 0..5; 204 real + 4 dump) staged once;
//      phys 16B chunk = logical ^ (rr & 15).
// Weights: 8 phases of (cc, taps 0-4 | 5-8), ping-pong buf0/buf1, staged one
// phase ahead. wbuf layout [tap_local][qk][f][8c].
__global__ __launch_bounds__(256, 1) void conv_gemm_kernel(
    const unsigned short* __restrict__ xp,
    const unsigned short* __restrict__ wpk,
    const float* __restrict__ bias,
    float* __restrict__ out)
{
    __shared__ alignas(16) unsigned short lds_x[208 * C_IN];    // 53,248 B
    __shared__ alignas(16) unsigned short lds_w[2][5 * 4096];   // 2 x 40,960 B

    const int tid  = threadIdx.x;
    const int lane = tid & 63;
    const int wave = tid >> 6;
    const int qk   = lane >> 4;      // 8-channel k-subgroup 0..3
    const int l15  = lane & 15;

    const int band = blockIdx.x & 7;
    const int n    = blockIdx.x >> 3;
    const int fh   = wave >> 1;
    const int rp   = wave & 1;
    const int f0   = fh * 64;

    // ---- issue x stage (once): 3328 16B chunks (rows 204..207 dump, src clamped)
    const unsigned short* xbase = xp + (unsigned)((n * HPAD + band * 4) * HPAD) * C_IN;
    #pragma unroll
    for (int i = 0; i < 13; ++i) {
        int p = tid + i * 256;
        int row = p >> 4;  if (row > 203) row = 203;
        int lc = (p ^ row) & 15;                      // logical chunk for phys p&15
        const unsigned short* src = xbase + row * C_IN + lc * 8;
        __builtin_amdgcn_global_load_lds(
            (const __attribute__((address_space(1))) void*)src,
            (__attribute__((address_space(3))) void*)(&lds_x[p * 8]),
            16, 0, 0);
    }

    // ---- weight stage helper: taps [t0, t0+nt) of chunk cc -> lds_w[buf]
    #define STAGE_W(ccv, t0v, ntv, bufv) do {                                   \
        const unsigned short* wsrc = wpk + ((ccv) * 9 + (t0v)) * 4096;          \
        _Pragma("unroll")                                                       \
        for (int j_ = 0; j_ < 2 * (ntv); ++j_) {                                \
            int p_ = tid + j_ * 256;                                            \
            __builtin_amdgcn_global_load_lds(                                   \
                (const __attribute__((address_space(1))) void*)(wsrc + p_ * 8), \
                (__attribute__((address_space(3))) void*)(&lds_w[bufv][p_ * 8]),\
                16, 0, 0);                                                      \
        }                                                                       \
    } while (0)

    STAGE_W(0, 0, 5, 0);   // phase 0 weights

    f32x4 acc[4][4];
    #pragma unroll
    for (int mi = 0; mi < 4; ++mi)
        #pragma unroll
        for (int ni = 0; ni < 4; ++ni)
            acc[mi][ni] = (f32x4){0.f, 0.f, 0.f, 0.f};

    // x row bases per ni: pos p = ni*16 + l15 -> row = p>>5, col = p&31
    int rrb[4];
    #pragma unroll
    for (int ni = 0; ni < 4; ++ni)
        rrb[ni] = (rp * 2 + (ni >> 1)) * HPAD + (ni & 1) * 16 + l15;

    // A-fragment base: f = f0 + mi*16 + l15, channels qk*8.. (FIX: fh*64 offset!)
    const int af_base = qk * 1024 + (f0 + l15) * 8;   // + tl*4096 + mi*128 shorts

    __syncthreads();   // x tile + phase-0 weights resident

    #define COMPUTE(bufv, T0, NT, ccv)                                          \
        _Pragma("unroll")                                                       \
        for (int tl = 0; tl < (NT); ++tl) {                                     \
            const int tap = (T0) + tl;                                          \
            const int r = tap / 3, s = tap - 3 * (tap / 3);                     \
            bf16x8 af[4], bf[4];                                                \
            _Pragma("unroll")                                                   \
            for (int mi = 0; mi < 4; ++mi)                                      \
                af[mi] = *(const bf16x8*)&lds_w[bufv][tl * 4096 + af_base + mi * 128]; \
            _Pragma("unroll")                                                   \
            for (int ni = 0; ni < 4; ++ni) {                                    \
                int rr = rrb[ni] + r * HPAD + s;                                \
                int ph = ((ccv) * 4 + qk) ^ (rr & 15);                          \
                bf[ni] = *(const bf16x8*)&lds_x[rr * C_IN + ph * 8];            \
            }                                                                   \
            _Pragma("unroll")                                                   \
            for (int mi = 0; mi < 4; ++mi)                                      \
                _Pragma("unroll")                                               \
                for (int ni = 0; ni < 4; ++ni)                                  \
                    acc[mi][ni] = __builtin_amdgcn_mfma_f32_16x16x32_bf16(      \
                        af[mi], bf[ni], acc[mi][ni], 0, 0, 0);                  \
        }

    for (int cc = 0; cc < 4; ++cc) {
        STAGE_W(cc, 5, 4, 1);          // issue taps 5-8 of cc -> buf1
        COMPUTE(0, 0, 5, cc);          // compute taps 0-4 from buf0
        __syncthreads();               // drain: buf1 ready, buf0 reusable
        if (cc < 3) STAGE_W(cc + 1, 0, 5, 0);   // issue taps 0-4 of cc+1 -> buf0
        COMPUTE(1, 5, 4, cc);          // compute taps 5-8 from buf1
        __syncthreads();               // drain: buf0 ready, buf1 reusable
    }

    // ---- epilogue: D row (f) = qk*4 + reg, col = l15
    const int h0 = band * 4 + rp * 2;
    #pragma unroll
    for (int mi = 0; mi < 4; ++mi) {
        const int f_base = f0 + mi * 16 + qk * 4;
        float bv[4];
        #pragma unroll
        for (int r2 = 0; r2 < 4; ++r2) bv[r2] = bias[f_base + r2];
        #pragma unroll
        for (int ni = 0; ni < 4; ++ni) {
            const int h  = h0 + (ni >> 1);
            const int w2 = (ni & 1) * 16 + l15;
            #pragma unroll
            for (int r2 = 0; r2 < 4; ++r2) {
                out[((unsigned)(n * F_OUT + f_base + r2) * HW + h) * HW + w2] =
                    acc[mi][ni][r2] + bv[r2];
            }
        }
    }
    #undef STAGE_W
    #undef COMPUTE
}

extern "C" void kernel_launch(void* const* d_in, const int* in_sizes, int n_in,
                              void* d_out, int out_size, void* d_ws, size_t ws_size,
                              hipStream_t stream) {
    const float* x = (const float*)d_in[0];
    const float* w = (const float*)d_in[1];
    const float* b = (const float*)d_in[2];
    float* out = (float*)d_out;

    unsigned short* xp  = (unsigned short*)d_ws;                   // 32*34*34*128 bf16
    unsigned short* wpk = xp + (size_t)N_IMG * HPAD * HPAD * C_IN; // 4*9*4*128*8 bf16

    pack_x_kernel<<<N_IMG * HPAD, 256, 0, stream>>>(x, xp);
    pack_w_kernel<<<576, 256, 0, stream>>>(w, wpk);
    conv_gemm_kernel<<<N_IMG * 8, 256, 0, stream>>>(xp, wpk, b, out);
}

// Round 4
// 86.060 us; speedup vs baseline: 1.1740x; 1.0632x over previous
//
#include <hip/hip_runtime.h>

// Conv2dfft == direct 3x3 cross-correlation, pad=1, + bias (FFT grid never wraps).
// x: [32,128,32,32] f32; w: [128,128,3,3] f32; b: [128] f32; out: [32,128,32,32] f32.
// R6: R5 + counted-vmcnt weight pipeline (T4). Wave tile 64f x 64pos (acc[4][4]).
// Grid 256 (1 block/CU, 124KB LDS), 4 waves. x staged ONCE (53KB, XOR-swizzled).
// Weights: 12 phases of 3 taps (24KB), TRIPLE-buffered, issued 2 phases ahead;
// s_waitcnt vmcnt(6) BEFORE each s_barrier (loads span 2 phases, never drain to 0
// in the loop). pack_x and pack_w fused into one launch.

typedef __attribute__((ext_vector_type(8))) short bf16x8;
typedef __attribute__((ext_vector_type(4))) float f32x4;

#define N_IMG 32
#define C_IN  128
#define F_OUT 128
#define HW    32
#define HPAD  34

__device__ __forceinline__ unsigned short f2bf(float f) {
    union { float f; unsigned u; } v; v.f = f;
    unsigned r = v.u + 0x7fffu + ((v.u >> 16) & 1u);   // RNE
    return (unsigned short)(r >> 16);
}

// ---- fused pack: blocks [0,1088): x -> [N,34,34,C] bf16 (zero border);
//      blocks [1088,1664): w -> [cc 4][tap 9][qk 4][f 128][c8 8] bf16
__global__ __launch_bounds__(256) void pack_kernel(const float* __restrict__ x,
                                                   const float* __restrict__ w,
                                                   unsigned short* __restrict__ xp,
                                                   unsigned short* __restrict__ wpk) {
    __shared__ unsigned short tile[C_IN * HPAD];   // [c][wp]
    const int tid = threadIdx.x;
    if (blockIdx.x < N_IMG * HPAD) {
        const int n   = blockIdx.x / HPAD;
        const int hp  = blockIdx.x - n * HPAD;
        const unsigned base_out = (unsigned)(n * HPAD + hp) * (HPAD * C_IN);
        if (hp >= 1 && hp <= 32) {
            const int h = hp - 1;
            #pragma unroll
            for (int i = 0; i < 16; ++i) {             // 4096 = 128c * 32w, coalesced reads
                int idx = tid + i * 256;
                int c = idx >> 5, ww = idx & 31;
                tile[c * HPAD + (ww + 1)] = f2bf(x[((n * C_IN + c) * HW + h) * HW + ww]);
            }
            if (tid < C_IN) { tile[tid * HPAD] = 0; tile[tid * HPAD + 33] = 0; }
            __syncthreads();
            #pragma unroll
            for (int i = 0; i < 17; ++i) {             // 4352 = 34wp * 128c, coalesced writes
                int idx = tid + i * 256;
                int wp = idx >> 7, c = idx & 127;
                xp[base_out + (unsigned)idx] = tile[c * HPAD + wp];
            }
        } else {
            #pragma unroll
            for (int i = 0; i < 17; ++i) {
                int idx = tid + i * 256;
                xp[base_out + (unsigned)idx] = 0;
            }
        }
    } else {
        int idx = (blockIdx.x - N_IMG * HPAD) * 256 + tid;   // < 147456
        int c8  = idx & 7;
        int f   = (idx >> 3) & 127;
        int qk  = (idx >> 10) & 3;
        int u   = idx >> 12;                           // 0..35 = cc*9 + tap
        int cc  = u / 9;
        int tap = u - cc * 9;
        wpk[idx] = f2bf(w[(f * C_IN + cc * 32 + qk * 8 + c8) * 9 + tap]);
    }
}

// ---------------- implicit-GEMM conv ----------------------------------------
// grid 256: (n 32) x (band 8: 4 output rows). Block 256 = 4 waves, 1 block/CU.
// Wave (fh = wave>>1, rp = wave&1): tile 64f x 64pos (2 rows x 32), acc[4][4].
// LDS: x tile (rows rr = dh*34+wp, dh 0..5; 204 real + 4 dump) staged once;
//      phys 16B chunk = logical ^ (rr & 15).
// Weights: 12 phases (cc, tap-triple), triple-buffer, staged TWO phases ahead.
__global__ __launch_bounds__(256, 1) void conv_gemm_kernel(
    const unsigned short* __restrict__ xp,
    const unsigned short* __restrict__ wpk,
    const float* __restrict__ bias,
    float* __restrict__ out)
{
    __shared__ alignas(16) unsigned short lds_x[208 * C_IN];    // 53,248 B
    __shared__ alignas(16) unsigned short lds_w[3][3 * 4096];   // 3 x 24,576 B

    const int tid  = threadIdx.x;
    const int lane = tid & 63;
    const int wave = tid >> 6;
    const int qk   = lane >> 4;      // 8-channel k-subgroup 0..3
    const int l15  = lane & 15;

    const int band = blockIdx.x & 7;
    const int n    = blockIdx.x >> 3;
    const int fh   = wave >> 1;
    const int rp   = wave & 1;
    const int f0   = fh * 64;

    // ---- issue x stage (once): 3328 16B chunks (rows 204..207 dump, src clamped)
    const unsigned short* xbase = xp + (unsigned)((n * HPAD + band * 4) * HPAD) * C_IN;
    #pragma unroll
    for (int i = 0; i < 13; ++i) {
        int p = tid + i * 256;
        int row = p >> 4;  if (row > 203) row = 203;
        int lc = (p ^ row) & 15;                      // logical chunk for phys p&15
        const unsigned short* src = xbase + row * C_IN + lc * 8;
        __builtin_amdgcn_global_load_lds(
            (const __attribute__((address_space(1))) void*)src,
            (__attribute__((address_space(3))) void*)(&lds_x[p * 8]),
            16, 0, 0);
    }

    // ---- weight stage: 3 taps (24KB) of chunk cc starting at tap t0 -> lds_w[buf]
    #define STAGE_W3(ccv, t0v, bufv) do {                                       \
        const unsigned short* wsrc = wpk + ((ccv) * 9 + (t0v)) * 4096;          \
        _Pragma("unroll")                                                       \
        for (int j_ = 0; j_ < 6; ++j_) {                                        \
            int p_ = tid + j_ * 256;                                            \
            __builtin_amdgcn_global_lds(0);                                     \
        }                                                                       \
    } while (0)
    #undef STAGE_W3
    #define STAGE_W3(ccv, t0v, bufv) do {                                       \
        const unsigned short* wsrc = wpk + ((ccv) * 9 + (t0v)) * 4096;          \
        _Pragma("unroll")                                                       \
        for (int j_ = 0; j_ < 6; ++j_) {                                        \
            int p_ = tid + j_ * 256;                                            \
            __builtin_amdgcn_global_load_lds(                                   \
                (const __attribute__((address_space(1))) void*)(wsrc + p_ * 8), \
                (__attribute__((address_space(3))) void*)(&lds_w[bufv][p_ * 8]),\
                16, 0, 0);                                                      \
        }                                                                       \
    } while (0)

    STAGE_W3(0, 0, 0);   // phase 0
    STAGE_W3(0, 3, 1);   // phase 1

    f32x4 acc[4][4];
    #pragma unroll
    for (int mi = 0; mi < 4; ++mi)
        #pragma unroll
        for (int ni = 0; ni < 4; ++ni)
            acc[mi][ni] = (f32x4){0.f, 0.f, 0.f, 0.f};

    // x row bases per ni: pos p = ni*16 + l15 -> row = p>>5, col = p&31
    int rrb[4];
    #pragma unroll
    for (int ni = 0; ni < 4; ++ni)
        rrb[ni] = (rp * 2 + (ni >> 1)) * HPAD + (ni & 1) * 16 + l15;

    // A-fragment base: f = f0 + mi*16 + l15, channels qk*8..
    const int af_base = qk * 1024 + (f0 + l15) * 8;   // + tl*4096 + mi*128 shorts

    // prologue: x + phase0 must be resident; phase1's 6 loads may stay in flight
    asm volatile("s_waitcnt vmcnt(6)" ::: "memory");
    __builtin_amdgcn_s_barrier();
    __builtin_amdgcn_sched_barrier(0);

    #define COMPUTE3(bufv, ccv, T0)                                             \
        _Pragma("unroll")                                                       \
        for (int tl = 0; tl < 3; ++tl) {                                        \
            const int tap = (T0) + tl;                                          \
            const int r = tap / 3, s = tap - 3 * (tap / 3);                     \
            bf16x8 af[4], bf[4];                                                \
            _Pragma("unroll")                                                   \
            for (int mi = 0; mi < 4; ++mi)                                      \
                af[mi] = *(const bf16x8*)&lds_w[bufv][tl * 4096 + af_base + mi * 128]; \
            _Pragma("unroll")                                                   \
            for (int ni = 0; ni < 4; ++ni) {                                    \
                int rr = rrb[ni] + r * HPAD + s;                                \
                int ph = ((ccv) * 4 + qk) ^ (rr & 15);                          \
                bf[ni] = *(const bf16x8*)&lds_x[rr * C_IN + ph * 8];            \
            }                                                                   \
            _Pragma("unroll")                                                   \
            for (int mi = 0; mi < 4; ++mi)                                      \
                _Pragma("unroll")                                               \
                for (int ni = 0; ni < 4; ++ni)                                  \
                    acc[mi][ni] = __builtin_amdgcn_mfma_f32_16x16x32_bf16(      \
                        af[mi], bf[ni], acc[mi][ni], 0, 0, 0);                  \
        }

    // phase p: stage p+2 (2 ahead), compute p, wait vmcnt(6) (p+1 done, p+2 in
    // flight), barrier. Wait is BEFORE the barrier -> all waves' phase-(p+1)
    // loads are LDS-visible once every wave passes it.
    #define PHASE_FULL(cc2, t02, b2, bcur, ccv, t0v) do {                       \
        STAGE_W3(cc2, t02, b2);                                                 \
        COMPUTE3(bcur, ccv, t0v);                                               \
        asm volatile("s_waitcnt vmcnt(6)" ::: "memory");                        \
        __builtin_amdgcn_s_barrier();                                           \
        __builtin_amdgcn_sched_barrier(0);                                      \
    } while (0)

    PHASE_FULL(0, 6, 2, 0, 0, 0);   // p0: stage p2 (cc0,t6)->buf2, compute cc0 t0
    PHASE_FULL(1, 0, 0, 1, 0, 3);   // p1: stage p3
    PHASE_FULL(1, 3, 1, 2, 0, 6);   // p2: stage p4
    PHASE_FULL(1, 6, 2, 0, 1, 0);   // p3: stage p5
    PHASE_FULL(2, 0, 0, 1, 1, 3);   // p4: stage p6
    PHASE_FULL(2, 3, 1, 2, 1, 6);   // p5: stage p7
    PHASE_FULL(2, 6, 2, 0, 2, 0);   // p6: stage p8
    PHASE_FULL(3, 0, 0, 1, 2, 3);   // p7: stage p9
    PHASE_FULL(3, 3, 1, 2, 2, 6);   // p8: stage p10
    PHASE_FULL(3, 6, 2, 0, 3, 0);   // p9: stage p11
    // p10: nothing left to stage; need p11 done before last phase
    COMPUTE3(1, 3, 3);
    asm volatile("s_waitcnt vmcnt(0)" ::: "memory");
    __builtin_amdgcn_s_barrier();
    __builtin_amdgcn_sched_barrier(0);
    // p11
    COMPUTE3(2, 3, 6);

    // ---- epilogue: D row (f) = qk*4 + reg, col = l15
    const int h0 = band * 4 + rp * 2;
    #pragma unroll
    for (int mi = 0; mi < 4; ++mi) {
        const int f_base = f0 + mi * 16 + qk * 4;
        float bv[4];
        #pragma unroll
        for (int r2 = 0; r2 < 4; ++r2) bv[r2] = bias[f_base + r2];
        #pragma unroll
        for (int ni = 0; ni < 4; ++ni) {
            const int h  = h0 + (ni >> 1);
            const int w2 = (ni & 1) * 16 + l15;
            #pragma unroll
            for (int r2 = 0; r2 < 4; ++r2) {
                out[((unsigned)(n * F_OUT + f_base + r2) * HW + h) * HW + w2] =
                    acc[mi][ni][r2] + bv[r2];
            }
        }
    }
    #undef STAGE_W3
    #undef COMPUTE3
    #undef PHASE_FULL
}

extern "C" void kernel_launch(void* const* d_in, const int* in_sizes, int n_in,
                              void* d_out, int out_size, void* d_ws, size_t ws_size,
                              hipStream_t stream) {
    const float* x = (const float*)d_in[0];
    const float* w = (const float*)d_in[1];
    const float* b = (const float*)d_in[2];
    float* out = (float*)d_out;

    unsigned short* xp  = (unsigned short*)d_ws;                   // 32*34*34*128 bf16
    unsigned short* wpk = xp + (size_t)N_IMG * HPAD * HPAD * C_IN; // 4*9*4*128*8 bf16

    pack_kernel<<<N_IMG * HPAD + 576, 256, 0, stream>>>(x, w, xp, wpk);
    conv_gemm_kernel<<<N_IMG * 8, 256, 0, stream>>>(xp, wpk, b, out);
}

// Round 5
// 83.758 us; speedup vs baseline: 1.2062x; 1.0275x over previous
//
#include <hip/hip_runtime.h>

// Conv2dfft == direct 3x3 cross-correlation, pad=1, + bias (FFT grid never wraps).
// x: [32,128,32,32] f32; w: [128,128,3,3] f32; b: [128] f32; out: [32,128,32,32] f32.
// R7: pack_x ELIMINATED. Each conv block packs its own 6-row x-tile: coalesced
// scalar f32 loads (8 consecutive channels per lane), in-register f2bf + pack,
// one ds_write_b128 per 16B chunk into the XOR-swizzled tile. Main loop identical
// to R6 (12 phases x 3 taps, triple-buffered weights, counted vmcnt(6), raw
// s_barrier). Grid 256 (1 block/CU, 124KB LDS). pack kernel now w-only (576 blocks).

typedef __attribute__((ext_vector_type(8))) short bf16x8;
typedef __attribute__((ext_vector_type(4))) float f32x4;

#define N_IMG 32
#define C_IN  128
#define F_OUT 128
#define HW    32
#define HPAD  34

__device__ __forceinline__ unsigned short f2bf(float f) {
    union { float f; unsigned u; } v; v.f = f;
    unsigned r = v.u + 0x7fffu + ((v.u >> 16) & 1u);   // RNE
    return (unsigned short)(r >> 16);
}

// ------- pack w: [F,C,3,3] f32 -> [cc 4][tap 9][qk 4][f 128][c8 8] bf16 -------
__global__ __launch_bounds__(256) void pack_w_kernel(const float* __restrict__ w,
                                                     unsigned short* __restrict__ wpk) {
    int idx = blockIdx.x * 256 + threadIdx.x;          // < 147456
    int c8  = idx & 7;
    int f   = (idx >> 3) & 127;
    int qk  = (idx >> 10) & 3;
    int u   = idx >> 12;                               // 0..35 = cc*9 + tap
    int cc  = u / 9;
    int tap = u - cc * 9;
    wpk[idx] = f2bf(w[(f * C_IN + cc * 32 + qk * 8 + c8) * 9 + tap]);
}

// ---------------- implicit-GEMM conv (with integrated x-pack) ----------------
// grid 256: (n 32) x (band 8: 4 output rows). Block 256 = 4 waves, 1 block/CU.
// Wave (fh = wave>>1, rp = wave&1): tile 64f x 64pos (2 rows x 32), acc[4][4].
// LDS x tile: 204 positions rr = dh*34 + wp (dh 0..5), 128 ch each;
//   16B chunk qc stored at phys chunk qc ^ (rr & 15).
// Weights: 12 phases (cc, tap-triple), triple-buffer, staged TWO phases ahead,
//   s_waitcnt vmcnt(6) before each barrier (never drains to 0 in the loop).
__global__ __launch_bounds__(256, 1) void conv_gemm_kernel(
    const float* __restrict__ x,
    const unsigned short* __restrict__ wpk,
    const float* __restrict__ bias,
    float* __restrict__ out)
{
    __shared__ alignas(16) unsigned short lds_x[204 * C_IN];    // 52,224 B
    __shared__ alignas(16) unsigned short lds_w[3][3 * 4096];   // 3 x 24,576 B

    const int tid  = threadIdx.x;
    const int lane = tid & 63;
    const int wave = tid >> 6;
    const int qk   = lane >> 4;      // 8-channel k-subgroup 0..3
    const int l15  = lane & 15;

    const int band = blockIdx.x & 7;
    const int n    = blockIdx.x >> 3;
    const int fh   = wave >> 1;
    const int rp   = wave & 1;
    const int f0   = fh * 64;

    // ================= x-pack prologue (replaces pack_x kernel) =============
    // Border chunks wp=0 / wp=33: zero, all 6 dh rows (192 chunks).
    if (tid < 192) {
        int dh = tid / 32, rem = tid & 31;
        int wp = (rem & 1) * 33, qc = rem >> 1;
        int rr = dh * 34 + wp;
        *(bf16x8*)&lds_x[rr * C_IN + ((qc ^ (rr & 15)) << 3)] =
            (bf16x8){0, 0, 0, 0, 0, 0, 0, 0};
    }
    // Interior: 6 rows x 8 c-groups of 16 (2 per wave). Lane: w = lane&31,
    // chalf = lane>>5 -> this lane owns channels c0..c0+7 at column w.
    {
        const int w_    = lane & 31;
        const int chalf = lane >> 5;
        for (int dh = 0; dh < 6; ++dh) {
            const int h = band * 4 - 1 + dh;
            const bool valid = (h >= 0) && (h < HW);
            #pragma unroll
            for (int g2 = 0; g2 < 2; ++g2) {
                const int c0 = (wave * 2 + g2) * 16 + chalf * 8;
                bf16x8 v;
                if (valid) {
                    #pragma unroll
                    for (int k = 0; k < 8; ++k) {
                        float f = x[((n * C_IN + (c0 + k)) * HW + h) * HW + w_];
                        v[k] = (short)f2bf(f);
                    }
                } else {
                    #pragma unroll
                    for (int k = 0; k < 8; ++k) v[k] = 0;
                }
                const int rr = dh * 34 + (w_ + 1);
                const int qc = c0 >> 3;               // logical 16B chunk 0..15
                *(bf16x8*)&lds_x[rr * C_IN + ((qc ^ (rr & 15)) << 3)] = v;
            }
        }
    }
    __builtin_amdgcn_sched_barrier(0);   // all x loads issued+consumed before W issues

    // ---- weight stage: 3 taps (24KB) of chunk cc starting at tap t0 -> lds_w[buf]
    #define STAGE_W3(ccv, t0v, bufv) do {                                       \
        const unsigned short* wsrc = wpk + ((ccv) * 9 + (t0v)) * 4096;          \
        _Pragma("unroll")                                                       \
        for (int j_ = 0; j_ < 6; ++j_) {                                        \
            int p_ = tid + j_ * 256;                                            \
            __builtin_amdgcn_global_load_lds(                                   \
                (const __attribute__((address_space(1))) void*)(wsrc + p_ * 8), \
                (__attribute__((address_space(3))) void*)(&lds_w[bufv][p_ * 8]),\
                16, 0, 0);                                                      \
        }                                                                       \
    } while (0)

    STAGE_W3(0, 0, 0);   // phase 0
    STAGE_W3(0, 3, 1);   // phase 1
    __builtin_amdgcn_sched_barrier(0);

    f32x4 acc[4][4];
    #pragma unroll
    for (int mi = 0; mi < 4; ++mi)
        #pragma unroll
        for (int ni = 0; ni < 4; ++ni)
            acc[mi][ni] = (f32x4){0.f, 0.f, 0.f, 0.f};

    // x position bases per ni: pos p = ni*16 + l15 -> row = p>>5, col = p&31
    int rrb[4];
    #pragma unroll
    for (int ni = 0; ni < 4; ++ni)
        rrb[ni] = (rp * 2 + (ni >> 1)) * HPAD + (ni & 1) * 16 + l15;

    // A-fragment base: f = f0 + mi*16 + l15, channels qk*8..
    const int af_base = qk * 1024 + (f0 + l15) * 8;   // + tl*4096 + mi*128 shorts

    // prologue: x ds_writes visible (lgkm), stage0 resident (vmcnt 6: stage1 in flight)
    asm volatile("s_waitcnt vmcnt(6) lgkmcnt(0)" ::: "memory");
    __builtin_amdgcn_s_barrier();
    __builtin_amdgcn_sched_barrier(0);

    #define COMPUTE3(bufv, ccv, T0)                                             \
        _Pragma("unroll")                                                       \
        for (int tl = 0; tl < 3; ++tl) {                                        \
            const int tap = (T0) + tl;                                          \
            const int r = tap / 3, s = tap - 3 * (tap / 3);                     \
            bf16x8 af[4], bf[4];                                                \
            _Pragma("unroll")                                                   \
            for (int mi = 0; mi < 4; ++mi)                                      \
                af[mi] = *(const bf16x8*)&lds_w[bufv][tl * 4096 + af_base + mi * 128]; \
            _Pragma("unroll")                                                   \
            for (int ni = 0; ni < 4; ++ni) {                                    \
                int rr = rrb[ni] + r * HPAD + s;                                \
                int ph = ((ccv) * 4 + qk) ^ (rr & 15);                          \
                bf[ni] = *(const bf16x8*)&lds_x[rr * C_IN + ph * 8];            \
            }                                                                   \
            _Pragma("unroll")                                                   \
            for (int mi = 0; mi < 4; ++mi)                                      \
                _Pragma("unroll")                                               \
                for (int ni = 0; ni < 4; ++ni)                                  \
                    acc[mi][ni] = __builtin_amdgcn_mfma_f32_16x16x32_bf16(      \
                        af[mi], bf[ni], acc[mi][ni], 0, 0, 0);                  \
        }

    // phase p: stage p+2 (2 ahead), compute p, wait vmcnt(6) (p+1 done, p+2 in
    // flight), barrier.
    #define PHASE_FULL(cc2, t02, b2, bcur, ccv, t0v) do {                       \
        STAGE_W3(cc2, t02, b2);                                                 \
        COMPUTE3(bcur, ccv, t0v);                                               \
        asm volatile("s_waitcnt vmcnt(6)" ::: "memory");                        \
        __builtin_amdgcn_s_barrier();                                           \
        __builtin_amdgcn_sched_barrier(0);                                      \
    } while (0)

    PHASE_FULL(0, 6, 2, 0, 0, 0);   // p0: stage p2 (cc0,t6)->buf2, compute cc0 t0
    PHASE_FULL(1, 0, 0, 1, 0, 3);   // p1: stage p3
    PHASE_FULL(1, 3, 1, 2, 0, 6);   // p2: stage p4
    PHASE_FULL(1, 6, 2, 0, 1, 0);   // p3: stage p5
    PHASE_FULL(2, 0, 0, 1, 1, 3);   // p4: stage p6
    PHASE_FULL(2, 3, 1, 2, 1, 6);   // p5: stage p7
    PHASE_FULL(2, 6, 2, 0, 2, 0);   // p6: stage p8
    PHASE_FULL(3, 0, 0, 1, 2, 3);   // p7: stage p9
    PHASE_FULL(3, 3, 1, 2, 2, 6);   // p8: stage p10
    PHASE_FULL(3, 6, 2, 0, 3, 0);   // p9: stage p11
    // p10: nothing left to stage; need p11 done before last phase
    COMPUTE3(1, 3, 3);
    asm volatile("s_waitcnt vmcnt(0)" ::: "memory");
    __builtin_amdgcn_s_barrier();
    __builtin_amdgcn_sched_barrier(0);
    // p11
    COMPUTE3(2, 3, 6);

    // ---- epilogue: D row (f) = qk*4 + reg, col = l15
    const int h0 = band * 4 + rp * 2;
    #pragma unroll
    for (int mi = 0; mi < 4; ++mi) {
        const int f_base = f0 + mi * 16 + qk * 4;
        float bv[4];
        #pragma unroll
        for (int r2 = 0; r2 < 4; ++r2) bv[r2] = bias[f_base + r2];
        #pragma unroll
        for (int ni = 0; ni < 4; ++ni) {
            const int h  = h0 + (ni >> 1);
            const int w2 = (ni & 1) * 16 + l15;
            #pragma unroll
            for (int r2 = 0; r2 < 4; ++r2) {
                out[((unsigned)(n * F_OUT + f_base + r2) * HW + h) * HW + w2] =
                    acc[mi][ni][r2] + bv[r2];
            }
        }
    }
    #undef STAGE_W3
    #undef COMPUTE3
    #undef PHASE_FULL
}

extern "C" void kernel_launch(void* const* d_in, const int* in_sizes, int n_in,
                              void* d_out, int out_size, void* d_ws, size_t ws_size,
                              hipStream_t stream) {
    const float* x = (const float*)d_in[0];
    const float* w = (const float*)d_in[1];
    const float* b = (const float*)d_in[2];
    float* out = (float*)d_out;

    unsigned short* wpk = (unsigned short*)d_ws;   // 4*9*4*128*8 bf16 = 294,912 B

    pack_w_kernel<<<576, 256, 0, stream>>>(w, wpk);
    conv_gemm_kernel<<<N_IMG * 8, 256, 0, stream>>>(x, wpk, b, out);
}